// Round 4
// baseline (79.280 us; speedup 1.0000x reference)
//
#include <hip/hip_runtime.h>
#include <math.h>

// Symmetric Hausdorff, B=8, N=M=4096, D=2, fp32.
// Round 9: move hk_partial's dot products to the MFMA pipe via 2-term
// _Float16 splits (hi+lo ~22 mantissa bits, residual 2^-22 ~ 1e-6 on dist).
//   acc = -2 p.q + |q|^2 from one v_mfma_f32_32x32x16_f16 per 32x32 tile:
//     k0-7:  A = -2*{qxh,qxh,qxl,qxl,qyh,qyh,qyl,qyl} (lanes 0-31, j=lane&31)
//            B =    {pxh,pxl,pxh,pxl,pyh,pyl,pyh,pyl} (lanes 0-31, i=lane&31)
//     k8-9:  A = {qqh,qql} (lanes 32-63), B = {1,1}   -> |q|^2 folded in
//   |p|^2 stays exact fp32, added AFTER the min (monotone => legal).
//   C/D: col=lane&31 = i (B-free), row=f(reg,lane>>5) = j (A-free) -> min over
//   j is in-lane over 16 acc regs (8 v_min3) + one __shfl_xor(32) at the end.
// Per 1024-pair tile: 1 ds_read_b128 + 1 MFMA (~8cyc) + 8 min3 + 16 acc-zero
// -> MFMA pipe 3.4us, VALU ~5us, LDS ~5us, overlapped: ~6us vs ~10us fp32 floor.
// hk_maxred/hk_final unchanged (JC=8). Fill ~41us is harness-fixed.

#define B 8
#define N 4096
#define TPB 256
#define JC 8              // j-chunks per (b,dir)
#define JTILE (N / JC)    // 512 j-points per block
#define NT (JTILE / 32)   // 16 j-tiles of 32
#define IBLK 128          // i per block = 4 waves x 32
#define NIB (N / IBLK)    // 32 i-blocks
#define ITILES (N / TPB)  // 16 i-tiles for the reduce stage

typedef _Float16 half8 __attribute__((ext_vector_type(8)));
typedef float f32x16 __attribute__((ext_vector_type(16)));

__global__ __launch_bounds__(TPB) void hk_partial(const float* __restrict__ pred,
                                                  const float* __restrict__ target,
                                                  float* __restrict__ pw) {
    const int ibk = blockIdx.x & (NIB - 1);
    const int jc  = blockIdx.x >> 5;       // NIB == 32
    const int b   = blockIdx.y;
    const int dir = blockIdx.z;

    const float2* __restrict__ P =
        reinterpret_cast<const float2*>(dir == 0 ? pred : target) + (size_t)b * N;
    const float2* __restrict__ Q =
        reinterpret_cast<const float2*>(dir == 0 ? target : pred) + (size_t)b * N
        + (size_t)jc * JTILE;

    // A-operand image: per j-tile, 64 lane-entries of 8 halfs (16 B). 16 KB.
    __shared__ half8 sA[NT * 64];

    for (int s = threadIdx.x; s < JTILE; s += TPB) {   // 2 iters
        float2 q = Q[s];
        _Float16 xh = (_Float16)q.x;
        _Float16 xl = (_Float16)(q.x - (float)xh);
        _Float16 yh = (_Float16)q.y;
        _Float16 yl = (_Float16)(q.y - (float)yh);
        float qq = fmaf(q.x, q.x, q.y * q.y);
        _Float16 qqh = (_Float16)qq;
        _Float16 qql = (_Float16)(qq - (float)qqh);
        _Float16 nxh = (_Float16)(-2.f * (float)xh);   // *2, negate: exact
        _Float16 nxl = (_Float16)(-2.f * (float)xl);
        _Float16 nyh = (_Float16)(-2.f * (float)yh);
        _Float16 nyl = (_Float16)(-2.f * (float)yl);
        const _Float16 z = (_Float16)0.f;
        int t = s >> 5, m = s & 31;
        sA[t * 64 + m]      = (half8){nxh, nxh, nxl, nxl, nyh, nyh, nyl, nyl};
        sA[t * 64 + 32 + m] = (half8){qqh, qql, z, z, z, z, z, z};
    }

    const int lane = threadIdx.x & 63;
    const int wave = threadIdx.x >> 6;
    const int col  = lane & 31;
    const int i    = ibk * IBLK + wave * 32 + col;

    // B-operand fragment (per-wave constant across the j-loop).
    half8 bf;
    float pp = 0.f;
    if (lane < 32) {
        float2 p = P[i];
        _Float16 xh = (_Float16)p.x;
        _Float16 xl = (_Float16)(p.x - (float)xh);
        _Float16 yh = (_Float16)p.y;
        _Float16 yl = (_Float16)(p.y - (float)yh);
        bf = (half8){xh, xl, xh, xl, yh, yl, yh, yl};
        pp = fmaf(p.x, p.x, p.y * p.y);
    } else {
        const _Float16 one = (_Float16)1.f;
        const _Float16 z   = (_Float16)0.f;
        bf = (half8){one, one, z, z, z, z, z, z};
    }

    __syncthreads();

    float rm[8];
    #pragma unroll
    for (int r = 0; r < 8; ++r) rm[r] = 3.402823466e38f;

    #pragma unroll 2
    for (int t = 0; t < NT; ++t) {
        half8 a = sA[t * 64 + lane];
        f32x16 acc = {};
        acc = __builtin_amdgcn_mfma_f32_32x32x16_f16(a, bf, acc, 0, 0, 0);
        #pragma unroll
        for (int r = 0; r < 8; ++r)
            rm[r] = fminf(rm[r], fminf(acc[2 * r], acc[2 * r + 1]));  // v_min3
    }

    float mn = fminf(fminf(fminf(rm[0], rm[1]), fminf(rm[2], rm[3])),
                     fminf(fminf(rm[4], rm[5]), fminf(rm[6], rm[7])));
    mn = fminf(mn, __shfl_xor(mn, 32, 64));   // combine lane-halves (j 16+16)

    if (lane < 32) {
        float* dst = pw + (size_t)((dir * B + b) * JC + jc) * N;
        dst[i] = mn + pp;   // |p|^2 restored after min
    }
}

// One block per (i-tile, b, dir): min over 8 jc (coalesced), block max-reduce,
// write to a private slot — no atomics, no init required.
__global__ __launch_bounds__(TPB) void hk_maxred(const float* __restrict__ pw,
                                                 float* __restrict__ pw2) {
    const int tile = blockIdx.x;
    const int b    = blockIdx.y;
    const int dir  = blockIdx.z;
    const int t    = threadIdx.x;

    const float* base = pw + (size_t)((dir * B + b) * JC) * N + tile * TPB + t;
    float mnv = base[0];
    #pragma unroll
    for (int jc = 1; jc < JC; ++jc) mnv = fminf(mnv, base[(size_t)jc * N]);

    float mx = mnv;
    #pragma unroll
    for (int off = 32; off > 0; off >>= 1)
        mx = fmaxf(mx, __shfl_down(mx, off, 64));

    __shared__ float sred[TPB / 64];
    if ((t & 63) == 0) sred[t >> 6] = mx;
    __syncthreads();
    if (t == 0) {
        float bm = sred[0];
        #pragma unroll
        for (int w = 1; w < TPB / 64; ++w) bm = fmaxf(bm, sred[w]);
        pw2[(dir * B + b) * ITILES + tile] = bm;   // [dir][b][tile]
    }
}

// Single block: 256 slots -> 16 (dir,b) maxes -> mean over b of sqrt(max(dirs)).
__global__ __launch_bounds__(64) void hk_final(const float* __restrict__ pw2,
                                               float* __restrict__ out) {
    const int t = threadIdx.x;
    __shared__ float h2[2 * B];
    if (t < 2 * B) {
        float mx = pw2[t * ITILES];
        #pragma unroll
        for (int k = 1; k < ITILES; ++k) mx = fmaxf(mx, pw2[t * ITILES + k]);
        h2[t] = mx;
    }
    __syncthreads();
    if (t == 0) {
        float s = 0.f;
        #pragma unroll
        for (int b = 0; b < B; ++b)
            s += sqrtf(fmaxf(fmaxf(h2[b], h2[B + b]), 0.f));
        out[0] = s * (1.0f / B);
    }
}

extern "C" void kernel_launch(void* const* d_in, const int* in_sizes, int n_in,
                              void* d_out, int out_size, void* d_ws, size_t ws_size,
                              hipStream_t stream) {
    const float* pred   = (const float*)d_in[0];
    const float* target = (const float*)d_in[1];
    float* out = (float*)d_out;
    float* pw  = (float*)d_ws;                       // 2*8*8*4096 floats = 2 MB
    float* pw2 = (float*)((char*)d_ws + (size_t)2 * B * JC * N * sizeof(float)); // 256 floats

    dim3 g1(NIB * JC, B, 2);     // 256 x 8 x 2 = 4096 blocks
    hk_partial<<<g1, TPB, 0, stream>>>(pred, target, pw);
    dim3 g2(ITILES, B, 2);       // 256 blocks
    hk_maxred<<<g2, TPB, 0, stream>>>(pw, pw2);
    hk_final<<<1, 64, 0, stream>>>(pw2, out);
}